// Round 1
// baseline (449.467 us; speedup 1.0000x reference)
//
#include <hip/hip_runtime.h>
#include <stdint.h>

typedef __bf16 bf16;
typedef __attribute__((ext_vector_type(8))) __bf16 bf16x8;
typedef __attribute__((ext_vector_type(4))) float f32x4;

#define LORA_SCALE 0.25f

// async global->LDS, 16B per lane. LDS dest is wave-uniform base + lane*16.
__device__ __forceinline__ void gload_lds16(const bf16* g, bf16* l) {
    __builtin_amdgcn_global_load_lds(
        (const __attribute__((address_space(1))) uint32_t*)g,
        (__attribute__((address_space(3))) uint32_t*)l,
        16, 0, 0);
}

__device__ __forceinline__ bf16x8 cvt8(const float* p) {
    f32x4 a = *(const f32x4*)p;
    f32x4 b = *(const f32x4*)(p + 4);
    bf16x8 r;
    r[0] = (bf16)a[0]; r[1] = (bf16)a[1]; r[2] = (bf16)a[2]; r[3] = (bf16)a[3];
    r[4] = (bf16)b[0]; r[5] = (bf16)b[1]; r[6] = (bf16)b[2]; r[7] = (bf16)b[3];
    return r;
}

// Convert W1 (n1 elems) and W2 (n2 elems) f32->bf16 in one launch.
__global__ __launch_bounds__(256)
void cvt_weights(const float* __restrict__ in1, bf16* __restrict__ out1, int n1,
                 const float* __restrict__ in2, bf16* __restrict__ out2, int n2) {
    const int64_t idx = (int64_t)(blockIdx.x * 256 + threadIdx.x) * 8;
    if (idx < n1) *(bf16x8*)&out1[idx] = cvt8(&in1[idx]);
    else          *(bf16x8*)&out2[idx - n1] = cvt8(&in2[idx - n1]);
}

// t1[m][r] = sum_k X[m][k] * Aall[aid][r][k]. 4 rows per wave. Also writes
// Xb = bf16(X). K=1024. Grid: M/16 blocks of 256.
__global__ __launch_bounds__(256)
void lora1(const float* __restrict__ X, const float* __restrict__ Aall,
           const int* __restrict__ adapter, float* __restrict__ T,
           bf16* __restrict__ Xb)
{
    const int K = 1024;
    const int gid = blockIdx.x * 256 + threadIdx.x;
    const int aid = adapter[0];
    const float* Aa = Aall + (int64_t)aid * 4 * K;
    const int wid  = gid >> 6;
    const int lane = threadIdx.x & 63;
    const int m0   = wid * 4;

    float acc[4][4];
    #pragma unroll
    for (int rr = 0; rr < 4; rr++)
        #pragma unroll
        for (int r = 0; r < 4; r++) acc[rr][r] = 0.f;

    #pragma unroll
    for (int it = 0; it < K / 512; it++) {
        const int k = it * 512 + lane * 8;
        float av[4][8];
        #pragma unroll
        for (int r = 0; r < 4; r++) {
            f32x4 a = *(const f32x4*)&Aa[r * K + k];
            f32x4 b = *(const f32x4*)&Aa[r * K + k + 4];
            av[r][0]=a[0]; av[r][1]=a[1]; av[r][2]=a[2]; av[r][3]=a[3];
            av[r][4]=b[0]; av[r][5]=b[1]; av[r][6]=b[2]; av[r][7]=b[3];
        }
        #pragma unroll
        for (int rr = 0; rr < 4; rr++) {
            const float* xp = X + (int64_t)(m0 + rr) * K + k;
            f32x4 a = *(const f32x4*)xp;
            f32x4 b = *(const f32x4*)(xp + 4);
            float xv[8] = {a[0],a[1],a[2],a[3],b[0],b[1],b[2],b[3]};
            bf16x8 xb;
            #pragma unroll
            for (int e = 0; e < 8; e++) xb[e] = (bf16)xv[e];
            *(bf16x8*)&Xb[(int64_t)(m0 + rr) * K + k] = xb;
            #pragma unroll
            for (int r = 0; r < 4; r++)
                #pragma unroll
                for (int e = 0; e < 8; e++)
                    acc[rr][r] += xv[e] * av[r][e];
        }
    }
    #pragma unroll
    for (int rr = 0; rr < 4; rr++)
        #pragma unroll
        for (int r = 0; r < 4; r++)
            #pragma unroll
            for (int off = 32; off >= 1; off >>= 1)
                acc[rr][r] += __shfl_xor(acc[rr][r], off);
    if (lane == 0) {
        #pragma unroll
        for (int rr = 0; rr < 4; rr++) {
            f32x4 t;
            t[0] = acc[rr][0]; t[1] = acc[rr][1]; t[2] = acc[rr][2]; t[3] = acc[rr][3];
            *(f32x4*)&T[(int64_t)(m0 + rr) * 4] = t;
        }
    }
}

// t2[m][r] = sum_p T2p[p][m][r], p < NP. One thread per (m,r).
__global__ __launch_bounds__(256)
void t2_reduce(const float* __restrict__ T2p, float* __restrict__ T2,
               int M, int NP) {
    const int i = blockIdx.x * 256 + threadIdx.x;   // (m*4 + r)
    float s = 0.f;
    for (int p = 0; p < NP; p++) s += T2p[(int64_t)p * M * 4 + i];
    T2[i] = s;
}

// C[m][n] = act( sum_k A[m][k]*Bm[n][k] + SCALE * sum_r Tlo[m][r]*Blo[aid][n][r] )
//
// 256x256 tile, BK=64, 512 threads = 8 waves (4M x 2N), 1 block/CU.
// 8-phase pipelined schedule (T3+T4 counted vmcnt, T5 setprio, T2-style XOR
// swizzle). LDS: 2 buffers x 4 units x 16KB = 128 KB. Unit = (operand,K-half):
//   u0 = A k[0:32), u1 = B k[0:32), u2 = A k[32:64), u3 = B k[32:64)
// Unit layout: elem(row 0..255, chunk q 0..3 of 8 bf16) at
//   row*32 + (q ^ ((row>>1)&3))*8   -> ds_read_b128 column slices are 2-way
// bank aliased (free, m136). Staging writes the unit LINEARLY via
// global_load_lds (lane l of wave w, load i -> bytes (i*512 + w*64 + l)*16);
// the inverse swizzle is applied to the per-lane GLOBAL source address.
//
// Pipeline (tile t, buf = t&1, 4 phases):
//   ph0: ds a(ks0) + b(nj0-3,ks0) | stage (t+1).u3 -> buf^1 | 16 MFMA
//   ph1: ds b(nj4-7,ks0)          | stage (t+2).u0 -> buf   | 16 MFMA
//   ph2: ds a(ks1) + b(nj0-3,ks1) | stage (t+2).u1 -> buf   | 16 MFMA
//   ph3: ds b(nj4-7,ks1)          | stage (t+2).u2 -> buf   | 16 MFMA
//        then s_waitcnt vmcnt(6) (vmcnt(0) only at the tail) -- loads stay in
//        flight across barriers; unit u is last READ in phase u and its (t+2)
//        overwrite issues in phase u+1, after that phase's trailing barrier.
// sched_barrier(0) after every s_barrier pins emitted order (s_barrier is
// IntrNoMem; without the fence ds_reads can be hoisted across it -> race).
template<bool RELU, typename CT, int PART, bool FUSET2>
__global__ __launch_bounds__(512, 2)
void gemm_lora8(const bf16* __restrict__ A,    // [M][K] bf16
                const bf16* __restrict__ Bm,   // [N][K] bf16 (torch [out,in])
                CT* __restrict__ C,            // [M][N]
                const float* __restrict__ Tlo, // [M][4]
                const float* __restrict__ Blo, // [NUM][N][4] f32
                const int* __restrict__ adapter,
                const float* __restrict__ A2,  // [NUM][4][N] f32 (FUSET2)
                float* __restrict__ T2p,       // [2*Nt][M][4] (FUSET2)
                int M, int N, int K)
{
    __shared__ alignas(16) bf16 smem[65536];   // 128 KB

    const int tid  = threadIdx.x;
    const int lane = tid & 63;
    const int w    = tid >> 6;
    const int quad = lane >> 4;
    const int l16  = lane & 15;

    // XCD-aware remap (8 XCDs; nwg % 8 == 0 for both launches -> bijective).
    int bx, by;
    {
        const int Nt = gridDim.x, Mt = gridDim.y;
        const int id = blockIdx.y * Nt + blockIdx.x;
        const int xcd = id & 7, k = id >> 3;
        if (PART == 0) { const int q = Nt >> 3; bx = xcd * q + (k % q); by = k / q; }
        else           { const int q = Mt >> 3; bx = k % Nt; by = xcd * q + (k / Nt); }
    }
    const int nBase = bx * 256;
    const int mBase = by * 256;
    const int wm = (w >> 1) * 64;                // wave M offset: 0/64/128/192
    const int wn = (w & 1) * 128;                // wave N offset: 0/128

    f32x4 acc[4][8];
    #pragma unroll
    for (int i = 0; i < 4; i++)
        #pragma unroll
        for (int j = 0; j < 8; j++)
            #pragma unroll
            for (int e = 0; e < 4; e++) acc[i][j][e] = 0.f;

    const bf16* gA = A  + (int64_t)mBase * K;
    const bf16* gB = Bm + (int64_t)nBase * K;

    // staging: thread -> (row, chunk). load 0 covers rows 0..127, load 1
    // covers rows 128..255 (of the tile). Global source pre-applies the
    // inverse chunk swizzle: q = (tid&3) ^ ((row>>1)&3), (row>>1)&3 == (tid>>3)&3.
    const int sq    = (tid & 3) ^ ((tid >> 3) & 3);
    const int srow  = ((tid >> 3) << 1) | ((tid >> 2) & 1);
    const bf16* sA0 = gA + (int64_t)srow * K + sq * 8;
    const bf16* sA1 = gA + (int64_t)(srow + 128) * K + sq * 8;
    const bf16* sB0 = gB + (int64_t)srow * K + sq * 8;
    const bf16* sB1 = gB + (int64_t)(srow + 128) * K + sq * 8;
    const int dstW  = w * 512;                   // wave-uniform LDS base (elems)

    // fragment reads: row = (wm|wn) + f*16 + l16; phys chunk = quad ^ ((l16>>1)&3)
    const int pc8  = (quad ^ ((l16 >> 1) & 3)) * 8;
    const int aOff = (wm + l16) * 32 + pc8;
    const int bOff = (wn + l16) * 32 + pc8;

    const int NT = K >> 6;

    auto stage = [&](const bf16* s0, const bf16* s1, int t, int uidx) {
        bf16* u = smem + ((t & 1) * 4 + uidx) * 8192;
        const int co = t * 64 + (uidx >> 1) * 32;   // k-tile + K-half offset
        gload_lds16(s0 + co, u + dstW);
        gload_lds16(s1 + co, u + dstW + 4096);
    };

    // prologue: tile 0 fully (u0..u3), then tile 1 u0..u2 (3 units in flight)
    stage(sA0, sA1, 0, 0); stage(sB0, sB1, 0, 1);
    stage(sA0, sA1, 0, 2); stage(sB0, sB1, 0, 3);
    if (NT > 1) {
        asm volatile("s_waitcnt vmcnt(4)" ::: "memory");
        stage(sA0, sA1, 1, 0); stage(sB0, sB1, 1, 1); stage(sA0, sA1, 1, 2);
        asm volatile("s_waitcnt vmcnt(6)" ::: "memory");
    } else {
        asm volatile("s_waitcnt vmcnt(0)" ::: "memory");
    }
    __builtin_amdgcn_s_barrier();
    __builtin_amdgcn_sched_barrier(0);

    for (int t = 0; t < NT; ++t) {
        const bf16* u0 = smem + (t & 1) * 32768;
        const bf16* u1 = u0 + 8192;
        const bf16* u2 = u0 + 16384;
        const bf16* u3 = u0 + 24576;
        const bool sNext  = (t + 1 < NT);
        const bool sNext2 = (t + 2 < NT);

        // ---- phase 0: (nj 0-3, ks0)
        bf16x8 a0[4], bA[4];
        #pragma unroll
        for (int mi = 0; mi < 4; mi++) a0[mi] = *(const bf16x8*)&u0[aOff + mi * 512];
        #pragma unroll
        for (int j = 0; j < 4; j++)   bA[j]  = *(const bf16x8*)&u1[bOff + j * 512];
        if (sNext) stage(sB0, sB1, t + 1, 3);
        __builtin_amdgcn_s_barrier();
        __builtin_amdgcn_sched_barrier(0);
        asm volatile("s_waitcnt lgkmcnt(0)" ::: "memory");
        __builtin_amdgcn_s_setprio(1);
        #pragma unroll
        for (int mi = 0; mi < 4; mi++)
            #pragma unroll
            for (int j = 0; j < 4; j++)
                acc[mi][j] = __builtin_amdgcn_mfma_f32_16x16x32_bf16(a0[mi], bA[j], acc[mi][j], 0, 0, 0);
        __builtin_amdgcn_s_setprio(0);
        __builtin_amdgcn_s_barrier();
        __builtin_amdgcn_sched_barrier(0);

        // ---- phase 1: (nj 4-7, ks0)
        bf16x8 bB[4];
        #pragma unroll
        for (int j = 0; j < 4; j++) bB[j] = *(const bf16x8*)&u1[bOff + (4 + j) * 512];
        if (sNext2) stage(sA0, sA1, t + 2, 0);
        __builtin_amdgcn_s_barrier();
        __builtin_amdgcn_sched_barrier(0);
        asm volatile("s_waitcnt lgkmcnt(0)" ::: "memory");
        __builtin_amdgcn_s_setprio(1);
        #pragma unroll
        for (int mi = 0; mi < 4; mi++)
            #pragma unroll
            for (int j = 0; j < 4; j++)
                acc[mi][4 + j] = __builtin_amdgcn_mfma_f32_16x16x32_bf16(a0[mi], bB[j], acc[mi][4 + j], 0, 0, 0);
        __builtin_amdgcn_s_setprio(0);
        __builtin_amdgcn_s_barrier();
        __builtin_amdgcn_sched_barrier(0);

        // ---- phase 2: (nj 0-3, ks1)
        bf16x8 a1[4], bC[4];
        #pragma unroll
        for (int mi = 0; mi < 4; mi++) a1[mi] = *(const bf16x8*)&u2[aOff + mi * 512];
        #pragma unroll
        for (int j = 0; j < 4; j++)   bC[j]  = *(const bf16x8*)&u3[bOff + j * 512];
        if (sNext2) stage(sB0, sB1, t + 2, 1);
        __builtin_amdgcn_s_barrier();
        __builtin_amdgcn_sched_barrier(0);
        asm volatile("s_waitcnt lgkmcnt(0)" ::: "memory");
        __builtin_amdgcn_s_setprio(1);
        #pragma unroll
        for (int mi = 0; mi < 4; mi++)
            #pragma unroll
            for (int j = 0; j < 4; j++)
                acc[mi][j] = __builtin_amdgcn_mfma_f32_16x16x32_bf16(a1[mi], bC[j], acc[mi][j], 0, 0, 0);
        __builtin_amdgcn_s_setprio(0);
        __builtin_amdgcn_s_barrier();
        __builtin_amdgcn_sched_barrier(0);

        // ---- phase 3: (nj 4-7, ks1)
        bf16x8 bD[4];
        #pragma unroll
        for (int j = 0; j < 4; j++) bD[j] = *(const bf16x8*)&u3[bOff + (4 + j) * 512];
        if (sNext2) stage(sA0, sA1, t + 2, 2);
        __builtin_amdgcn_s_barrier();
        __builtin_amdgcn_sched_barrier(0);
        asm volatile("s_waitcnt lgkmcnt(0)" ::: "memory");
        __builtin_amdgcn_s_setprio(1);
        #pragma unroll
        for (int mi = 0; mi < 4; mi++)
            #pragma unroll
            for (int j = 0; j < 4; j++)
                acc[mi][4 + j] = __builtin_amdgcn_mfma_f32_16x16x32_bf16(a1[mi], bD[j], acc[mi][4 + j], 0, 0, 0);
        __builtin_amdgcn_s_setprio(0);
        if (sNext) {
            if (sNext2) asm volatile("s_waitcnt vmcnt(6)" ::: "memory");
            else        asm volatile("s_waitcnt vmcnt(0)" ::: "memory");
        }
        __builtin_amdgcn_s_barrier();
        __builtin_amdgcn_sched_barrier(0);
    }

    // ---------------- Epilogue (all global loads strictly after the loop,
    // so in-loop vmcnt counts were exact; staging fully drained here).
    const int aid = adapter[0];
    const float* Ba = Blo + (int64_t)aid * N * 4;

    f32x4 bv[8];
    #pragma unroll
    for (int j = 0; j < 8; j++) {
        const int f = nBase + wn + j * 16 + l16;
        bv[j] = *(const f32x4*)&Ba[(int64_t)f * 4];
    }

    float a2v[8][4];
    if constexpr (FUSET2) {
        const float* A2a = A2 + (int64_t)aid * 4 * N;
        #pragma unroll
        for (int j = 0; j < 8; j++) {
            const int f = nBase + wn + j * 16 + l16;
            #pragma unroll
            for (int r2 = 0; r2 < 4; r2++)
                a2v[j][r2] = A2a[(int64_t)r2 * N + f];
        }
    }
    float* T2row = FUSET2 ? T2p + (int64_t)(bx * 2 + (w & 1)) * M * 4 : nullptr;

    if constexpr (sizeof(CT) == 2) {
        bf16* scratch = smem + w * (16 * 136);       // per-wave, wave-local
        #pragma unroll
        for (int mi = 0; mi < 4; mi++) {
            f32x4 tv[4];
            #pragma unroll
            for (int r = 0; r < 4; r++) {
                const int m = mBase + wm + mi * 16 + quad * 4 + r;
                tv[r] = *(const f32x4*)&Tlo[(int64_t)m * 4];
            }
            float tp[4][4];
            if constexpr (FUSET2)
                #pragma unroll
                for (int r = 0; r < 4; r++)
                    #pragma unroll
                    for (int r2 = 0; r2 < 4; r2++) tp[r][r2] = 0.f;
            #pragma unroll
            for (int j = 0; j < 8; j++) {
                #pragma unroll
                for (int r = 0; r < 4; r++) {
                    const float d = tv[r][0] * bv[j][0] + tv[r][1] * bv[j][1]
                                  + tv[r][2] * bv[j][2] + tv[r][3] * bv[j][3];
                    float v = acc[mi][j][r] + LORA_SCALE * d;
                    if (RELU) v = v > 0.f ? v : 0.f;
                    if constexpr (FUSET2)
                        #pragma unroll
                        for (int r2 = 0; r2 < 4; r2++) tp[r][r2] += v * a2v[j][r2];
                    scratch[(quad * 4 + r) * 136 + j * 16 + l16] = (bf16)v;
                }
            }
            if constexpr (FUSET2) {
                #pragma unroll
                for (int r = 0; r < 4; r++)
                    #pragma unroll
                    for (int r2 = 0; r2 < 4; r2++)
                        #pragma unroll
                        for (int off = 8; off >= 1; off >>= 1)
                            tp[r][r2] += __shfl_xor(tp[r][r2], off);
                if (l16 == 0) {
                    #pragma unroll
                    for (int r = 0; r < 4; r++) {
                        const int m = mBase + wm + mi * 16 + quad * 4 + r;
                        f32x4 o;
                        o[0] = tp[r][0]; o[1] = tp[r][1];
                        o[2] = tp[r][2]; o[3] = tp[r][3];
                        *(f32x4*)&T2row[(int64_t)m * 4] = o;    // plain store
                    }
                }
            }
            #pragma unroll
            for (int it = 0; it < 4; it++) {
                const int cid = it * 64 + lane;
                const int row = cid >> 4, c8 = cid & 15;
                bf16x8 vv = *(const bf16x8*)&scratch[row * 136 + c8 * 8];
                const int m = mBase + wm + mi * 16 + row;
                *(bf16x8*)&C[(int64_t)m * N + nBase + wn + c8 * 8] = vv;
            }
        }
    } else {
        float* scratchf = (float*)smem + w * (16 * 132);
        #pragma unroll
        for (int mi = 0; mi < 4; mi++) {
            f32x4 tv[4];
            #pragma unroll
            for (int r = 0; r < 4; r++) {
                const int m = mBase + wm + mi * 16 + quad * 4 + r;
                tv[r] = *(const f32x4*)&Tlo[(int64_t)m * 4];
            }
            #pragma unroll
            for (int j = 0; j < 8; j++) {
                #pragma unroll
                for (int r = 0; r < 4; r++) {
                    const float d = tv[r][0] * bv[j][0] + tv[r][1] * bv[j][1]
                                  + tv[r][2] * bv[j][2] + tv[r][3] * bv[j][3];
                    float v = acc[mi][j][r] + LORA_SCALE * d;
                    if (RELU) v = v > 0.f ? v : 0.f;
                    scratchf[(quad * 4 + r) * 132 + j * 16 + l16] = v;
                }
            }
            #pragma unroll
            for (int it = 0; it < 8; it++) {
                const int cid = it * 64 + lane;
                const int row = cid >> 5, c4 = cid & 31;
                f32x4 vv = *(const f32x4*)&scratchf[row * 132 + c4 * 4];
                const int m = mBase + wm + mi * 16 + row;
                *(f32x4*)&C[(int64_t)m * N + nBase + wn + c4 * 4] = vv;
            }
        }
    }
}

extern "C" void kernel_launch(void* const* d_in, const int* in_sizes, int n_in,
                              void* d_out, int out_size, void* d_ws, size_t ws_size,
                              hipStream_t stream) {
    const float* x  = (const float*)d_in[0];
    const float* W1 = (const float*)d_in[1];
    const float* A1 = (const float*)d_in[2];
    const float* B1 = (const float*)d_in[3];
    const float* W2 = (const float*)d_in[4];
    const float* A2 = (const float*)d_in[5];
    const float* B2 = (const float*)d_in[6];
    const int* adapter = (const int*)d_in[7];
    float* out = (float*)d_out;

    const int M = 16384, D = 1024, F = 4096;
    const int Nt1 = F / 256;                       // 16 N-tiles in GEMM1

    // ws layout (~184.5 MiB):
    bf16*  h   = (bf16*)d_ws;                      // M*F bf16 = 128 MiB
    bf16*  xb  = h + (size_t)M * F;                // M*D bf16 =  32 MiB
    bf16*  wb1 = xb + (size_t)M * D;               // F*D bf16 =   8 MiB
    bf16*  wb2 = wb1 + (size_t)F * D;              // D*F bf16 =   8 MiB
    float* t1  = (float*)(wb2 + (size_t)D * F);    // M*4 f32
    float* t2  = t1 + (size_t)M * 4;               // M*4 f32
    float* t2p = t2 + (size_t)M * 4;               // 32*M*4 f32 = 8 MiB

    // t1 = x @ A1a^T ; xb = bf16(x)
    lora1<<<M / 16, 256, 0, stream>>>(x, A1, adapter, t1, xb);
    // wb1 = bf16(W1), wb2 = bf16(W2)
    cvt_weights<<<(2 * F * D) / 2048, 256, 0, stream>>>(W1, wb1, F * D, W2, wb2, D * F);
    // h = relu(xb @ wb1^T + scale * t1 @ B1a^T); t2p partials (fused, no atomics)
    dim3 g1(F / 256, M / 256);                     // 16 x 64
    gemm_lora8<true, bf16, 0, true><<<g1, 512, 0, stream>>>(
        xb, wb1, h, t1, B1, adapter, A2, t2p, M, F, D);
    // t2 = reduce(t2p)
    t2_reduce<<<(M * 4) / 256, 256, 0, stream>>>(t2p, t2, M, 2 * Nt1);
    // out = h @ wb2^T + scale * t2 @ B2a^T  -> f32
    dim3 g2(D / 256, M / 256);                     // 4 x 64
    gemm_lora8<false, float, 1, false><<<g2, 512, 0, stream>>>(
        h, wb2, out, t2, B2, adapter, nullptr, nullptr, M, D, F);
}

// Round 2
// 430.735 us; speedup vs baseline: 1.0435x; 1.0435x over previous
//
#include <hip/hip_runtime.h>
#include <stdint.h>

typedef __bf16 bf16;
typedef __attribute__((ext_vector_type(8))) __bf16 bf16x8;
typedef __attribute__((ext_vector_type(4))) float f32x4;

#define LORA_SCALE 0.25f

// async global->LDS, 16B per lane. LDS dest is wave-uniform base + lane*16.
__device__ __forceinline__ void gload_lds16(const bf16* g, bf16* l) {
    __builtin_amdgcn_global_load_lds(
        (const __attribute__((address_space(1))) uint32_t*)g,
        (__attribute__((address_space(3))) uint32_t*)l,
        16, 0, 0);
}

__device__ __forceinline__ bf16x8 cvt8(const float* p) {
    f32x4 a = *(const f32x4*)p;
    f32x4 b = *(const f32x4*)(p + 4);
    bf16x8 r;
    r[0] = (bf16)a[0]; r[1] = (bf16)a[1]; r[2] = (bf16)a[2]; r[3] = (bf16)a[3];
    r[4] = (bf16)b[0]; r[5] = (bf16)b[1]; r[6] = (bf16)b[2]; r[7] = (bf16)b[3];
    return r;
}

// Convert W1 (n1 elems) and W2 (n2 elems) f32->bf16 in one launch.
__global__ __launch_bounds__(256)
void cvt_weights(const float* __restrict__ in1, bf16* __restrict__ out1, int n1,
                 const float* __restrict__ in2, bf16* __restrict__ out2, int n2) {
    const int64_t idx = (int64_t)(blockIdx.x * 256 + threadIdx.x) * 8;
    if (idx < n1) *(bf16x8*)&out1[idx] = cvt8(&in1[idx]);
    else          *(bf16x8*)&out2[idx - n1] = cvt8(&in2[idx - n1]);
}

// t1[m][r] = sum_k X[m][k] * Aall[aid][r][k]. 4 rows per wave. Also writes
// Xb = bf16(X). K=1024. Grid: M/16 blocks of 256.
__global__ __launch_bounds__(256)
void lora1(const float* __restrict__ X, const float* __restrict__ Aall,
           const int* __restrict__ adapter, float* __restrict__ T,
           bf16* __restrict__ Xb)
{
    const int K = 1024;
    const int gid = blockIdx.x * 256 + threadIdx.x;
    const int aid = adapter[0];
    const float* Aa = Aall + (int64_t)aid * 4 * K;
    const int wid  = gid >> 6;
    const int lane = threadIdx.x & 63;
    const int m0   = wid * 4;

    float acc[4][4];
    #pragma unroll
    for (int rr = 0; rr < 4; rr++)
        #pragma unroll
        for (int r = 0; r < 4; r++) acc[rr][r] = 0.f;

    #pragma unroll
    for (int it = 0; it < K / 512; it++) {
        const int k = it * 512 + lane * 8;
        float av[4][8];
        #pragma unroll
        for (int r = 0; r < 4; r++) {
            f32x4 a = *(const f32x4*)&Aa[r * K + k];
            f32x4 b = *(const f32x4*)&Aa[r * K + k + 4];
            av[r][0]=a[0]; av[r][1]=a[1]; av[r][2]=a[2]; av[r][3]=a[3];
            av[r][4]=b[0]; av[r][5]=b[1]; av[r][6]=b[2]; av[r][7]=b[3];
        }
        #pragma unroll
        for (int rr = 0; rr < 4; rr++) {
            const float* xp = X + (int64_t)(m0 + rr) * K + k;
            f32x4 a = *(const f32x4*)xp;
            f32x4 b = *(const f32x4*)(xp + 4);
            float xv[8] = {a[0],a[1],a[2],a[3],b[0],b[1],b[2],b[3]};
            bf16x8 xb;
            #pragma unroll
            for (int e = 0; e < 8; e++) xb[e] = (bf16)xv[e];
            *(bf16x8*)&Xb[(int64_t)(m0 + rr) * K + k] = xb;
            #pragma unroll
            for (int r = 0; r < 4; r++)
                #pragma unroll
                for (int e = 0; e < 8; e++)
                    acc[rr][r] += xv[e] * av[r][e];
        }
    }
    #pragma unroll
    for (int rr = 0; rr < 4; rr++)
        #pragma unroll
        for (int r = 0; r < 4; r++)
            #pragma unroll
            for (int off = 32; off >= 1; off >>= 1)
                acc[rr][r] += __shfl_xor(acc[rr][r], off);
    if (lane == 0) {
        #pragma unroll
        for (int rr = 0; rr < 4; rr++) {
            f32x4 t;
            t[0] = acc[rr][0]; t[1] = acc[rr][1]; t[2] = acc[rr][2]; t[3] = acc[rr][3];
            *(f32x4*)&T[(int64_t)(m0 + rr) * 4] = t;
        }
    }
}

// t2[m][r] = sum_p T2p[p][m][r], p < NP. One thread per (m,r).
__global__ __launch_bounds__(256)
void t2_reduce(const float* __restrict__ T2p, float* __restrict__ T2,
               int M, int NP) {
    const int i = blockIdx.x * 256 + threadIdx.x;   // (m*4 + r)
    float s = 0.f;
    for (int p = 0; p < NP; p++) s += T2p[(int64_t)p * M * 4 + i];
    T2[i] = s;
}

#define MFMA16(AF, BF, JOFF)                                                     \
    __builtin_amdgcn_s_setprio(1);                                              \
    _Pragma("unroll")                                                            \
    for (int mi = 0; mi < 4; mi++)                                               \
        _Pragma("unroll")                                                        \
        for (int j = 0; j < 4; j++)                                              \
            acc[mi][JOFF + j] = __builtin_amdgcn_mfma_f32_16x16x32_bf16(         \
                AF[mi], BF[j], acc[mi][JOFF + j], 0, 0, 0);                      \
    __builtin_amdgcn_s_setprio(0);

// C[m][n] = act( sum_k A[m][k]*Bm[n][k] + SCALE * sum_r Tlo[m][r]*Blo[aid][n][r] )
//
// 256x256 tile, BK=64, 512 threads = 8 waves (4M x 2N), 1 block/CU.
// SINGLE-barrier phases with frags software-pipelined one phase ahead:
// at phase p entry lgkmcnt(0) waits frags(p) (drained during MFMA(p-1));
// then issue frags(p+1) ds_reads + one stage; MFMA(p); one publish barrier.
// LDS drain of frags(p+1) hides under MFMA(p) -- the previous dual-barrier
// version serialized drain and MFMA (measured: MfmaUtil pinned at 31%).
//
// Units: u0=A k[0:32) u1=B k[0:32) u2=A k[32:64) u3=B k[32:64), 16KB each,
// double-buffered (128KB). Chunk-XOR layout: elem(row,q) at
// row*32 + (q ^ ((row>>1)&3))*8 -> full-wave b128 reads are bank-even.
// Staging writes LINEAR via global_load_lds; inverse swizzle on global src.
//
// Stage schedule (tile t): ph0:(t+1).u3  ph1:(t+2).u0  ph2:(t+2).u1  ph3:(t+2).u2
// Waits: vmcnt(4) in ph2 (leaves (t+2).u0,u1; drains (t+1).u3) then the ph2
// barrier publishes ALL of tile t+1 -> ph3 preload of next-tile frags is safe.
// Unit-overwrite safety: unit uX last frag-WAIT is at phX entry; phX-end
// barrier precedes the (t+2).uX stage issued in ph(X+1).
template<bool RELU, typename CT, int PART, bool FUSET2>
__global__ __launch_bounds__(512, 2)
void gemm_lora9(const bf16* __restrict__ A,    // [M][K] bf16
                const bf16* __restrict__ Bm,   // [N][K] bf16 (torch [out,in])
                CT* __restrict__ C,            // [M][N]
                const float* __restrict__ Tlo, // [M][4]
                const float* __restrict__ Blo, // [NUM][N][4] f32
                const int* __restrict__ adapter,
                const float* __restrict__ A2,  // [NUM][4][N] f32 (FUSET2)
                float* __restrict__ T2p,       // [2*Nt][M][4] (FUSET2)
                int M, int N, int K)
{
    __shared__ alignas(16) bf16 smem[65536];   // 128 KB

    const int tid  = threadIdx.x;
    const int lane = tid & 63;
    const int w    = tid >> 6;
    const int quad = lane >> 4;
    const int l16  = lane & 15;

    // XCD-aware remap (8 XCDs; nwg % 8 == 0 for both launches -> bijective).
    int bx, by;
    {
        const int Nt = gridDim.x, Mt = gridDim.y;
        const int id = blockIdx.y * Nt + blockIdx.x;
        const int xcd = id & 7, k = id >> 3;
        if (PART == 0) { const int q = Nt >> 3; bx = xcd * q + (k % q); by = k / q; }
        else           { const int q = Mt >> 3; bx = k % Nt; by = xcd * q + (k / Nt); }
    }
    const int nBase = bx * 256;
    const int mBase = by * 256;
    const int wm = (w >> 1) * 64;                // wave M offset: 0/64/128/192
    const int wn = (w & 1) * 128;                // wave N offset: 0/128

    f32x4 acc[4][8];
    #pragma unroll
    for (int i = 0; i < 4; i++)
        #pragma unroll
        for (int j = 0; j < 8; j++)
            #pragma unroll
            for (int e = 0; e < 4; e++) acc[i][j][e] = 0.f;

    const bf16* gA = A  + (int64_t)mBase * K;
    const bf16* gB = Bm + (int64_t)nBase * K;

    // staging: thread -> (row, chunk); inverse chunk swizzle on global source.
    const int sq    = (tid & 3) ^ ((tid >> 3) & 3);
    const int srow  = ((tid >> 3) << 1) | ((tid >> 2) & 1);
    const bf16* sA0 = gA + (int64_t)srow * K + sq * 8;
    const bf16* sA1 = gA + (int64_t)(srow + 128) * K + sq * 8;
    const bf16* sB0 = gB + (int64_t)srow * K + sq * 8;
    const bf16* sB1 = gB + (int64_t)(srow + 128) * K + sq * 8;
    const int dstW  = w * 512;                   // wave-uniform LDS base (elems)

    // fragment reads: row = (wm|wn) + f*16 + l16; phys chunk = quad ^ ((l16>>1)&3)
    const int pc8  = (quad ^ ((l16 >> 1) & 3)) * 8;
    const int aOff = (wm + l16) * 32 + pc8;
    const int bOff = (wn + l16) * 32 + pc8;

    const int NT = K >> 6;

    auto stage = [&](const bf16* s0, const bf16* s1, int t, int uidx) {
        bf16* u = smem + ((t & 1) * 4 + uidx) * 8192;
        const int co = t * 64 + (uidx >> 1) * 32;   // k-tile + K-half offset
        gload_lds16(s0 + co, u + dstW);
        gload_lds16(s1 + co, u + dstW + 4096);
    };

    // prologue: tile 0 fully, then tile 1 u0..u2 -> invariant: 6 outstanding.
    stage(sA0, sA1, 0, 0); stage(sB0, sB1, 0, 1);
    stage(sA0, sA1, 0, 2); stage(sB0, sB1, 0, 3);
    if (NT > 1) {
        stage(sA0, sA1, 1, 0); stage(sB0, sB1, 1, 1); stage(sA0, sA1, 1, 2);
        asm volatile("s_waitcnt vmcnt(6)" ::: "memory");
    } else {
        asm volatile("s_waitcnt vmcnt(0)" ::: "memory");
    }
    __builtin_amdgcn_s_barrier();
    __builtin_amdgcn_sched_barrier(0);

    // frag register sets (all statically indexed)
    bf16x8 aX[4], aY[4], bX[4], bY[4];
    {   // preload phase-0 frags of tile 0 (u0, u1-lo)
        const bf16* p0 = smem;
        const bf16* p1 = smem + 8192;
        #pragma unroll
        for (int i = 0; i < 4; i++) aX[i] = *(const bf16x8*)&p0[aOff + i * 512];
        #pragma unroll
        for (int j = 0; j < 4; j++) bX[j] = *(const bf16x8*)&p1[bOff + j * 512];
    }

    for (int t = 0; t < NT; ++t) {
        const bf16* ub = smem + (t & 1) * 32768;
        const bf16* u1 = ub + 8192;
        const bf16* u2 = ub + 16384;
        const bf16* u3 = ub + 24576;
        const bf16* n0 = smem + ((t + 1) & 1) * 32768;
        const bf16* n1 = n0 + 8192;
        const bool sNext  = (t + 1 < NT);
        const bool sNext2 = (t + 2 < NT);

        // ---- phase 0: MFMA(aX,bX) -> acc[:,0..3] (ks0); preload bY <= u1-hi
        asm volatile("s_waitcnt lgkmcnt(0)" ::: "memory");
        __builtin_amdgcn_sched_barrier(0);
        #pragma unroll
        for (int j = 0; j < 4; j++) bY[j] = *(const bf16x8*)&u1[bOff + (4 + j) * 512];
        if (sNext) stage(sB0, sB1, t + 1, 3);
        MFMA16(aX, bX, 0)
        __builtin_amdgcn_s_barrier();
        __builtin_amdgcn_sched_barrier(0);

        // ---- phase 1: MFMA(aX,bY) -> acc[:,4..7] (ks0); preload aY<=u2, bX<=u3-lo
        asm volatile("s_waitcnt lgkmcnt(0)" ::: "memory");
        __builtin_amdgcn_sched_barrier(0);
        #pragma unroll
        for (int i = 0; i < 4; i++) aY[i] = *(const bf16x8*)&u2[aOff + i * 512];
        #pragma unroll
        for (int j = 0; j < 4; j++) bX[j] = *(const bf16x8*)&u3[bOff + j * 512];
        if (sNext2) stage(sA0, sA1, t + 2, 0);
        MFMA16(aX, bY, 4)
        __builtin_amdgcn_s_barrier();
        __builtin_amdgcn_sched_barrier(0);

        // ---- phase 2: MFMA(aY,bX) -> acc[:,0..3] (ks1); preload bY <= u3-hi
        asm volatile("s_waitcnt lgkmcnt(0)" ::: "memory");
        __builtin_amdgcn_sched_barrier(0);
        #pragma unroll
        for (int j = 0; j < 4; j++) bY[j] = *(const bf16x8*)&u3[bOff + (4 + j) * 512];
        if (sNext2) stage(sB0, sB1, t + 2, 1);
        if (sNext2)      asm volatile("s_waitcnt vmcnt(4)" ::: "memory");
        else if (sNext)  asm volatile("s_waitcnt vmcnt(0)" ::: "memory");
        MFMA16(aY, bX, 0)
        __builtin_amdgcn_s_barrier();      // publishes ALL of tile t+1
        __builtin_amdgcn_sched_barrier(0);

        // ---- phase 3: MFMA(aY,bY) -> acc[:,4..7] (ks1); preload next-tile aX,bX
        asm volatile("s_waitcnt lgkmcnt(0)" ::: "memory");
        __builtin_amdgcn_sched_barrier(0);
        if (sNext) {
            #pragma unroll
            for (int i = 0; i < 4; i++) aX[i] = *(const bf16x8*)&n0[aOff + i * 512];
            #pragma unroll
            for (int j = 0; j < 4; j++) bX[j] = *(const bf16x8*)&n1[bOff + j * 512];
        }
        if (sNext2) stage(sA0, sA1, t + 2, 2);
        MFMA16(aY, bY, 4)
        __builtin_amdgcn_s_barrier();
        __builtin_amdgcn_sched_barrier(0);
    }

    // ---------------- Epilogue (unchanged; all waves past final barrier).
    const int aid = adapter[0];
    const float* Ba = Blo + (int64_t)aid * N * 4;

    f32x4 bv[8];
    #pragma unroll
    for (int j = 0; j < 8; j++) {
        const int f = nBase + wn + j * 16 + l16;
        bv[j] = *(const f32x4*)&Ba[(int64_t)f * 4];
    }

    float a2v[8][4];
    if constexpr (FUSET2) {
        const float* A2a = A2 + (int64_t)aid * 4 * N;
        #pragma unroll
        for (int j = 0; j < 8; j++) {
            const int f = nBase + wn + j * 16 + l16;
            #pragma unroll
            for (int r2 = 0; r2 < 4; r2++)
                a2v[j][r2] = A2a[(int64_t)r2 * N + f];
        }
    }
    float* T2row = FUSET2 ? T2p + (int64_t)(bx * 2 + (w & 1)) * M * 4 : nullptr;

    if constexpr (sizeof(CT) == 2) {
        bf16* scratch = smem + w * (16 * 136);       // per-wave, wave-local
        #pragma unroll
        for (int mi = 0; mi < 4; mi++) {
            f32x4 tv[4];
            #pragma unroll
            for (int r = 0; r < 4; r++) {
                const int m = mBase + wm + mi * 16 + quad * 4 + r;
                tv[r] = *(const f32x4*)&Tlo[(int64_t)m * 4];
            }
            float tp[4][4];
            if constexpr (FUSET2)
                #pragma unroll
                for (int r = 0; r < 4; r++)
                    #pragma unroll
                    for (int r2 = 0; r2 < 4; r2++) tp[r][r2] = 0.f;
            #pragma unroll
            for (int j = 0; j < 8; j++) {
                #pragma unroll
                for (int r = 0; r < 4; r++) {
                    const float d = tv[r][0] * bv[j][0] + tv[r][1] * bv[j][1]
                                  + tv[r][2] * bv[j][2] + tv[r][3] * bv[j][3];
                    float v = acc[mi][j][r] + LORA_SCALE * d;
                    if (RELU) v = v > 0.f ? v : 0.f;
                    if constexpr (FUSET2)
                        #pragma unroll
                        for (int r2 = 0; r2 < 4; r2++) tp[r][r2] += v * a2v[j][r2];
                    scratch[(quad * 4 + r) * 136 + j * 16 + l16] = (bf16)v;
                }
            }
            if constexpr (FUSET2) {
                #pragma unroll
                for (int r = 0; r < 4; r++)
                    #pragma unroll
                    for (int r2 = 0; r2 < 4; r2++)
                        #pragma unroll
                        for (int off = 8; off >= 1; off >>= 1)
                            tp[r][r2] += __shfl_xor(tp[r][r2], off);
                if (l16 == 0) {
                    #pragma unroll
                    for (int r = 0; r < 4; r++) {
                        const int m = mBase + wm + mi * 16 + quad * 4 + r;
                        f32x4 o;
                        o[0] = tp[r][0]; o[1] = tp[r][1];
                        o[2] = tp[r][2]; o[3] = tp[r][3];
                        *(f32x4*)&T2row[(int64_t)m * 4] = o;    // plain store
                    }
                }
            }
            #pragma unroll
            for (int it = 0; it < 4; it++) {
                const int cid = it * 64 + lane;
                const int row = cid >> 4, c8 = cid & 15;
                bf16x8 vv = *(const bf16x8*)&scratch[row * 136 + c8 * 8];
                const int m = mBase + wm + mi * 16 + row;
                *(bf16x8*)&C[(int64_t)m * N + nBase + wn + c8 * 8] = vv;
            }
        }
    } else {
        float* scratchf = (float*)smem + w * (16 * 132);
        #pragma unroll
        for (int mi = 0; mi < 4; mi++) {
            f32x4 tv[4];
            #pragma unroll
            for (int r = 0; r < 4; r++) {
                const int m = mBase + wm + mi * 16 + quad * 4 + r;
                tv[r] = *(const f32x4*)&Tlo[(int64_t)m * 4];
            }
            #pragma unroll
            for (int j = 0; j < 8; j++) {
                #pragma unroll
                for (int r = 0; r < 4; r++) {
                    const float d = tv[r][0] * bv[j][0] + tv[r][1] * bv[j][1]
                                  + tv[r][2] * bv[j][2] + tv[r][3] * bv[j][3];
                    float v = acc[mi][j][r] + LORA_SCALE * d;
                    if (RELU) v = v > 0.f ? v : 0.f;
                    scratchf[(quad * 4 + r) * 132 + j * 16 + l16] = v;
                }
            }
            #pragma unroll
            for (int it = 0; it < 8; it++) {
                const int cid = it * 64 + lane;
                const int row = cid >> 5, c4 = cid & 31;
                f32x4 vv = *(const f32x4*)&scratchf[row * 132 + c4 * 4];
                const int m = mBase + wm + mi * 16 + row;
                *(f32x4*)&C[(int64_t)m * N + nBase + wn + c4 * 4] = vv;
            }
        }
    }
}

extern "C" void kernel_launch(void* const* d_in, const int* in_sizes, int n_in,
                              void* d_out, int out_size, void* d_ws, size_t ws_size,
                              hipStream_t stream) {
    const float* x  = (const float*)d_in[0];
    const float* W1 = (const float*)d_in[1];
    const float* A1 = (const float*)d_in[2];
    const float* B1 = (const float*)d_in[3];
    const float* W2 = (const float*)d_in[4];
    const float* A2 = (const float*)d_in[5];
    const float* B2 = (const float*)d_in[6];
    const int* adapter = (const int*)d_in[7];
    float* out = (float*)d_out;

    const int M = 16384, D = 1024, F = 4096;
    const int Nt1 = F / 256;                       // 16 N-tiles in GEMM1

    // ws layout (~184.5 MiB):
    bf16*  h   = (bf16*)d_ws;                      // M*F bf16 = 128 MiB
    bf16*  xb  = h + (size_t)M * F;                // M*D bf16 =  32 MiB
    bf16*  wb1 = xb + (size_t)M * D;               // F*D bf16 =   8 MiB
    bf16*  wb2 = wb1 + (size_t)F * D;              // D*F bf16 =   8 MiB
    float* t1  = (float*)(wb2 + (size_t)D * F);    // M*4 f32
    float* t2  = t1 + (size_t)M * 4;               // M*4 f32
    float* t2p = t2 + (size_t)M * 4;               // 32*M*4 f32 = 8 MiB

    // t1 = x @ A1a^T ; xb = bf16(x)
    lora1<<<M / 16, 256, 0, stream>>>(x, A1, adapter, t1, xb);
    // wb1 = bf16(W1), wb2 = bf16(W2)
    cvt_weights<<<(2 * F * D) / 2048, 256, 0, stream>>>(W1, wb1, F * D, W2, wb2, D * F);
    // h = relu(xb @ wb1^T + scale * t1 @ B1a^T); t2p partials (fused, no atomics)
    dim3 g1(F / 256, M / 256);                     // 16 x 64
    gemm_lora9<true, bf16, 0, true><<<g1, 512, 0, stream>>>(
        xb, wb1, h, t1, B1, adapter, A2, t2p, M, F, D);
    // t2 = reduce(t2p)
    t2_reduce<<<(M * 4) / 256, 256, 0, stream>>>(t2p, t2, M, 2 * Nt1);
    // out = h @ wb2^T + scale * t2 @ B2a^T  -> f32
    dim3 g2(D / 256, M / 256);                     // 4 x 64
    gemm_lora9<false, float, 1, false><<<g2, 512, 0, stream>>>(
        h, wb2, out, t2, B2, adapter, nullptr, nullptr, M, D, F);
}